// Round 1
// baseline (147.155 us; speedup 1.0000x reference)
//
#include <hip/hip_runtime.h>
#include <math.h>

// CIoU loss, fp32, N = 4194304.
// Memory-bound: 134 MB in / 4 B out. Two-kernel deterministic reduction:
//   k1: grid-stride elementwise CIoU -> per-block partial sums in d_ws
//   k2: single block reduces partials in double, writes mean.

#define EPS 1e-6f
#define NBLOCKS 2048
#define NTHREADS 256

__global__ __launch_bounds__(NTHREADS) void ciou_partial_kernel(
    const float4* __restrict__ pred,   // N boxes, xyxy
    const float4* __restrict__ tgt,    // N boxes, xyxy
    float* __restrict__ partials,      // NBLOCKS outputs
    int n)
{
    const float inv_pi2_4 = 4.0f / (float)(M_PI * M_PI);
    float acc = 0.0f;

    int stride = gridDim.x * blockDim.x;
    for (int i = blockIdx.x * blockDim.x + threadIdx.x; i < n; i += stride) {
        float4 p = pred[i];
        float4 t = tgt[i];

        // widths/heights (inputs guaranteed positive by construction)
        float pw = p.z - p.x, ph = p.w - p.y;
        float tw = t.z - t.x, th = t.w - t.y;
        float area_p = pw * ph;
        float area_t = tw * th;

        // intersection
        float ix = fminf(p.z, t.z) - fmaxf(p.x, t.x);
        float iy = fminf(p.w, t.w) - fmaxf(p.y, t.y);
        ix = fmaxf(ix, 0.0f);
        iy = fmaxf(iy, 0.0f);
        float inter = ix * iy;
        float uni = area_p + area_t - inter;
        float iou = inter / fmaxf(uni, EPS);

        // center distance (factor 0.5 applied once per axis)
        float dcx = 0.5f * ((p.x + p.z) - (t.x + t.z));
        float dcy = 0.5f * ((p.y + p.w) - (t.y + t.w));
        float center_d = dcx * dcx + dcy * dcy;

        // enclosing-box diagonal
        float ex = fmaxf(p.z, t.z) - fminf(p.x, t.x);
        float ey = fmaxf(p.w, t.w) - fminf(p.y, t.y);
        float diag_d = ex * ex + ey * ey;

        // aspect-ratio term
        float da = atanf(tw / fmaxf(th, EPS)) - atanf(pw / fmaxf(ph, EPS));
        float v = inv_pi2_4 * da * da;
        float alpha = v / (1.0f - iou + v + EPS);

        float ciou = iou - center_d / fmaxf(diag_d, EPS) + alpha * v;
        acc += 1.0f - ciou;
    }

    // wave-64 reduce
    #pragma unroll
    for (int off = 32; off > 0; off >>= 1)
        acc += __shfl_down(acc, off, 64);

    // block reduce across 4 waves
    __shared__ float wsum[NTHREADS / 64];
    int lane = threadIdx.x & 63;
    int wid  = threadIdx.x >> 6;
    if (lane == 0) wsum[wid] = acc;
    __syncthreads();
    if (threadIdx.x == 0) {
        float b = wsum[0];
        #pragma unroll
        for (int w = 1; w < NTHREADS / 64; ++w) b += wsum[w];
        partials[blockIdx.x] = b;
    }
}

__global__ __launch_bounds__(NTHREADS) void ciou_finalize_kernel(
    const float* __restrict__ partials, float* __restrict__ out, int nblocks, float inv_n)
{
    // single block; sum in double for accuracy on the ~4e6-magnitude total
    double acc = 0.0;
    for (int i = threadIdx.x; i < nblocks; i += NTHREADS)
        acc += (double)partials[i];

    #pragma unroll
    for (int off = 32; off > 0; off >>= 1)
        acc += __shfl_down(acc, off, 64);

    __shared__ double wsum[NTHREADS / 64];
    int lane = threadIdx.x & 63;
    int wid  = threadIdx.x >> 6;
    if (lane == 0) wsum[wid] = acc;
    __syncthreads();
    if (threadIdx.x == 0) {
        double b = wsum[0];
        #pragma unroll
        for (int w = 1; w < NTHREADS / 64; ++w) b += wsum[w];
        out[0] = (float)(b * (double)inv_n);
    }
}

extern "C" void kernel_launch(void* const* d_in, const int* in_sizes, int n_in,
                              void* d_out, int out_size, void* d_ws, size_t ws_size,
                              hipStream_t stream)
{
    const float4* pred = (const float4*)d_in[0];
    const float4* tgt  = (const float4*)d_in[1];
    int n = in_sizes[0] / 4;   // in_sizes counts flat elements (N*4 floats)

    float* partials = (float*)d_ws;   // NBLOCKS * 4 bytes, every slot written each launch
    float* out = (float*)d_out;

    ciou_partial_kernel<<<NBLOCKS, NTHREADS, 0, stream>>>(pred, tgt, partials, n);
    ciou_finalize_kernel<<<1, NTHREADS, 0, stream>>>(partials, out, NBLOCKS, 1.0f / (float)n);
}

// Round 3
// 146.502 us; speedup vs baseline: 1.0045x; 1.0045x over previous
//
#include <hip/hip_runtime.h>
#include <math.h>

// CIoU loss, fp32, N = 4194304.
// Round 3 (= round 2 resubmit; bench never ran). Latency-bound fix:
// 8-deep upfront register loads (MLP) + single-atan identity
// atan(a)-atan(b) = atan((a-b)/(1+ab)) -> atan((tw*ph-pw*th)/(th*ph+tw*pw)).
// Two-kernel deterministic reduction unchanged.

#define EPS 1e-6f
#define NBLOCKS 2048
#define NTHREADS 256
#define PER_THREAD 8

__device__ __forceinline__ float ciou_loss(float4 p, float4 t)
{
    const float inv_pi2_4 = 4.0f / (float)(M_PI * M_PI);

    float pw = p.z - p.x, ph = p.w - p.y;
    float tw = t.z - t.x, th = t.w - t.y;
    float area_p = pw * ph;
    float area_t = tw * th;

    float ix = fminf(p.z, t.z) - fmaxf(p.x, t.x);
    float iy = fminf(p.w, t.w) - fmaxf(p.y, t.y);
    ix = fmaxf(ix, 0.0f);
    iy = fmaxf(iy, 0.0f);
    float inter = ix * iy;
    float uni = area_p + area_t - inter;
    float iou = inter / fmaxf(uni, EPS);

    float dcx = 0.5f * ((p.x + p.z) - (t.x + t.z));
    float dcy = 0.5f * ((p.y + p.w) - (t.y + t.w));
    float center_d = dcx * dcx + dcy * dcy;

    float ex = fmaxf(p.z, t.z) - fminf(p.x, t.x);
    float ey = fmaxf(p.w, t.w) - fminf(p.y, t.y);
    float diag_d = ex * ex + ey * ey;

    // atan(tw/th) - atan(pw/ph) == atan((tw*ph - pw*th) / (th*ph + tw*pw))
    // valid since both ratios are > 0 (wh > 1e-3 by construction); den > 0.
    float num = tw * ph - pw * th;
    float den = th * ph + tw * pw;
    float da = atanf(num / den);
    float v = inv_pi2_4 * da * da;
    float alpha = v / (1.0f - iou + v + EPS);

    float ciou = iou - center_d / fmaxf(diag_d, EPS) + alpha * v;
    return 1.0f - ciou;
}

__global__ __launch_bounds__(NTHREADS) void ciou_partial_kernel(
    const float4* __restrict__ pred,
    const float4* __restrict__ tgt,
    float* __restrict__ partials,
    int n)
{
    float acc = 0.0f;
    const int tid = blockIdx.x * NTHREADS + threadIdx.x;
    const int stride = NBLOCKS * NTHREADS;

    if (n == stride * PER_THREAD) {
        // fast path: all 16 loads issued upfront -> 256B/thread in flight
        float4 p[PER_THREAD], t[PER_THREAD];
        #pragma unroll
        for (int k = 0; k < PER_THREAD; ++k) {
            int i = tid + k * stride;
            p[k] = pred[i];
            t[k] = tgt[i];
        }
        #pragma unroll
        for (int k = 0; k < PER_THREAD; ++k)
            acc += ciou_loss(p[k], t[k]);
    } else {
        for (int i = tid; i < n; i += stride)
            acc += ciou_loss(pred[i], tgt[i]);
    }

    // wave-64 reduce
    #pragma unroll
    for (int off = 32; off > 0; off >>= 1)
        acc += __shfl_down(acc, off, 64);

    __shared__ float wsum[NTHREADS / 64];
    int lane = threadIdx.x & 63;
    int wid  = threadIdx.x >> 6;
    if (lane == 0) wsum[wid] = acc;
    __syncthreads();
    if (threadIdx.x == 0) {
        float b = wsum[0];
        #pragma unroll
        for (int w = 1; w < NTHREADS / 64; ++w) b += wsum[w];
        partials[blockIdx.x] = b;
    }
}

__global__ __launch_bounds__(NTHREADS) void ciou_finalize_kernel(
    const float* __restrict__ partials, float* __restrict__ out, int nblocks, float inv_n)
{
    double acc = 0.0;
    for (int i = threadIdx.x; i < nblocks; i += NTHREADS)
        acc += (double)partials[i];

    #pragma unroll
    for (int off = 32; off > 0; off >>= 1)
        acc += __shfl_down(acc, off, 64);

    __shared__ double wsum[NTHREADS / 64];
    int lane = threadIdx.x & 63;
    int wid  = threadIdx.x >> 6;
    if (lane == 0) wsum[wid] = acc;
    __syncthreads();
    if (threadIdx.x == 0) {
        double b = wsum[0];
        #pragma unroll
        for (int w = 1; w < NTHREADS / 64; ++w) b += wsum[w];
        out[0] = (float)(b * (double)inv_n);
    }
}

extern "C" void kernel_launch(void* const* d_in, const int* in_sizes, int n_in,
                              void* d_out, int out_size, void* d_ws, size_t ws_size,
                              hipStream_t stream)
{
    const float4* pred = (const float4*)d_in[0];
    const float4* tgt  = (const float4*)d_in[1];
    int n = in_sizes[0] / 4;

    float* partials = (float*)d_ws;
    float* out = (float*)d_out;

    ciou_partial_kernel<<<NBLOCKS, NTHREADS, 0, stream>>>(pred, tgt, partials, n);
    ciou_finalize_kernel<<<1, NTHREADS, 0, stream>>>(partials, out, NBLOCKS, 1.0f / (float)n);
}